// Round 3
// baseline (732.260 us; speedup 1.0000x reference)
//
#include <hip/hip_runtime.h>

typedef unsigned short u16;
typedef __attribute__((ext_vector_type(8))) short short8;
typedef __attribute__((ext_vector_type(4))) float f32x4;
typedef __attribute__((ext_vector_type(4))) unsigned short u16x4;
typedef __attribute__((ext_vector_type(2))) unsigned u32x2;

#define NN 262144
#define CC 256
#define RR 64
#define GG 1024

// LDS byte-offset swizzle for row-major [node][feat] bf16 tiles: XOR node low
// bits into the 16B-slot bits -> 2-way max bank aliasing on ds_read_b128 (free).
#define SWZ(b, n) ((b) ^ (((n) & 7) << 4))

// ws layout (bytes):
//   0        : 6 bf16 weight matrices, 16384 elems each (w1g,w2g,w1l,w2l,w1a,w2a)
//   196608   : seg float [1024][256]  (raw sums; k_attn scales by 1/cnt)
//   1245184  : cnt int [1024]

static __device__ __forceinline__ u16 f2bf(float f) {
  unsigned u = __builtin_bit_cast(unsigned, f);
  u += 0x7fffu + ((u >> 16) & 1u);   // RNE to bf16
  return (u16)(u >> 16);
}

static __device__ __forceinline__ unsigned cvt_pk_bf16(float lo, float hi) {
  unsigned r;
  asm("v_cvt_pk_bf16_f32 %0, %1, %2" : "=v"(r) : "v"(lo), "v"(hi));
  return r;
}

static __device__ __forceinline__ void lgkm0() {
  __asm__ volatile("s_waitcnt lgkmcnt(0)" ::: "memory");
}

#define MFMA16(a, b, c) __builtin_amdgcn_mfma_f32_16x16x32_bf16((a), (b), (c), 0, 0, 0)

// ---- weight fp32 -> bf16 conversion ----
__global__ void k_cvt(const float* __restrict__ a0, const float* __restrict__ a1,
                      const float* __restrict__ a2, const float* __restrict__ a3,
                      const float* __restrict__ a4, const float* __restrict__ a5,
                      u16* __restrict__ dst) {
  int m = blockIdx.x >> 4;
  const float* s = (m == 0) ? a0 : (m == 1) ? a1 : (m == 2) ? a2
                 : (m == 3) ? a3 : (m == 4) ? a4 : a5;
  int off = (((blockIdx.x & 15) << 8) | threadIdx.x) << 2;
  f32x4 v = *(const f32x4*)(s + off);
  u16x4 p;
  p[0] = f2bf(v[0]); p[1] = f2bf(v[1]); p[2] = f2bf(v[2]); p[3] = f2bf(v[3]);
  *(u16x4*)(dst + m * 16384 + off) = p;
}

// ============================================================================
// Block = 64 nodes, 4 waves, feature-split. LDS = exactly 32768 B -> 5
// blocks/CU. Regions are TIME-SHARED (barriers protect each transition):
//   phase A: x/h  [64][256] bf16 swizzled, bytes 0..32768 (node stride 512)
//   phase B: z    [64][64]  bf16 swizzled, bytes 0..8192  (node stride 128)
//   phase C: out/seg slabs: wave*4352 (4x4352=17408); k_glb lb at 20480
// ============================================================================

// ---- K1: glb MLP + segment sums/counts ----
__global__ __launch_bounds__(256, 5) void k_glb(
    const float* __restrict__ x, const u16* __restrict__ wbf,
    const int* __restrict__ bidx, const float* __restrict__ pa,
    float* __restrict__ seg, int* __restrict__ cnt) {
  __shared__ __align__(16) char smem[32768];
  const int tid = threadIdx.x;
  const int wave = tid >> 6, lane = tid & 63;
  const int low = lane & 15, quad = lane >> 4;
  const int node0 = blockIdx.x << 6;
  const float alpha = pa[0];
  const u16* w1 = wbf;              // glb_w1 [64][256]
  const u16* w2 = wbf + 16384;      // glb_w2 [256][64]

  // early: bidx into register (consumed after layer1)
  int myb_lb = (tid < 64) ? bidx[node0 + tid] : 0;

  // ---- stage x -> swizzled bf16 [64][256] ----
  const float* xsrc = x + (size_t)node0 * CC;
#pragma unroll
  for (int k = 0; k < 16; k++) {
    int f = k * 1024 + tid * 4;
    f32x4 v = *(const f32x4*)(xsrc + f);
    int node = f >> 8;
    u32x2 p;
    p[0] = cvt_pk_bf16(v[0], v[1]);
    p[1] = cvt_pk_bf16(v[2], v[3]);
    *(u32x2*)(smem + SWZ(node * 512 + (f & 255) * 2, node)) = p;
  }
  __syncthreads();

  // ---- layer1: wave's 16 feats x all 64 nodes ----
  f32x4 z[4] = {};
  const u16* w1p = w1 + (wave * 16 + low) * CC;
#pragma unroll
  for (int ks = 0; ks < 8; ks++) {
    short8 wa = *(const short8*)(w1p + ks * 32 + quad * 8);
#pragma unroll
    for (int nt = 0; nt < 4; nt++) {
      int node = nt * 16 + low;
      short8 xf = *(const short8*)(smem + SWZ(node * 512 + ks * 64 + quad * 16, node));
      z[nt] = MFMA16(wa, xf, z[nt]);
    }
  }
  __syncthreads();   // all x reads done; z overlay + lb may now overwrite

  // PReLU + stage z [64][64] bf16 at offset 0; lb at 20480
  if (tid < 64) ((int*)(smem + 20480))[tid] = myb_lb;
#pragma unroll
  for (int nt = 0; nt < 4; nt++) {
    float v0 = z[nt][0], v1 = z[nt][1], v2 = z[nt][2], v3 = z[nt][3];
    v0 = v0 >= 0.f ? v0 : alpha * v0;
    v1 = v1 >= 0.f ? v1 : alpha * v1;
    v2 = v2 >= 0.f ? v2 : alpha * v2;
    v3 = v3 >= 0.f ? v3 : alpha * v3;
    int node = nt * 16 + low;
    u32x2 p;
    p[0] = cvt_pk_bf16(v0, v1);
    p[1] = cvt_pk_bf16(v2, v3);
    *(u32x2*)(smem + SWZ(node * 128 + wave * 32 + quad * 8, node)) = p;
  }
  __syncthreads();   // z + lb visible

  const int* lbp = (const int*)(smem + 20480);

  // node counts (per-wave 16-node chunk, run-length on sorted bidx)
  if (lane == 0) {
    int base = wave * 16;
    int cur = lbp[base], rl = 0;
#pragma unroll
    for (int n = 0; n < 16; n++) {
      int b = lbp[base + n];
      if (b != cur) { atomicAdd(cnt + cur, rl); rl = 0; cur = b; }
      rl++;
    }
    atomicAdd(cnt + cur, rl);
  }

  // ---- layer2: wave's 64 feats x all 64 nodes ----
  f32x4 g[4][4] = {};   // [nt][mt]
#pragma unroll
  for (int ks2 = 0; ks2 < 2; ks2++) {
    short8 zf[4];
#pragma unroll
    for (int nt = 0; nt < 4; nt++) {
      int node = nt * 16 + low;
      zf[nt] = *(const short8*)(smem + SWZ(node * 128 + ks2 * 64 + quad * 16, node));
    }
#pragma unroll
    for (int mt = 0; mt < 4; mt++) {
      short8 wa = *(const short8*)(w2 + (wave * 64 + mt * 16 + low) * RR + ks2 * 32 + quad * 8);
#pragma unroll
      for (int nt = 0; nt < 4; nt++)
        g[nt][mt] = MFMA16(wa, zf[nt], g[nt][mt]);
    }
  }
  __syncthreads();   // z reads done; slab overlay may overwrite (lb untouched)

  // ---- segment reduce: per nt-tile, stage [16][68] f32 slab, run-length flush ----
  float* slab = (float*)(smem + wave * 4352);
#pragma unroll
  for (int nt = 0; nt < 4; nt++) {
#pragma unroll
    for (int mt = 0; mt < 4; mt++)
      *(f32x4*)(slab + low * 68 + mt * 16 + quad * 4) = g[nt][mt];
    lgkm0();
    float acc = 0.f;
    int cur = lbp[nt * 16];
#pragma unroll
    for (int n = 0; n < 16; n++) {
      int b = lbp[nt * 16 + n];
      if (b != cur) {
        atomicAdd(seg + (size_t)cur * CC + wave * 64 + lane, acc);
        acc = 0.f; cur = b;
      }
      acc += slab[n * 68 + lane];
    }
    atomicAdd(seg + (size_t)cur * CC + wave * 64 + lane, acc);
    lgkm0();
  }
}

// ---- K3: local MLP + gather(1/cnt fused) + attn MLP + sigmoid ----
__global__ __launch_bounds__(256, 5) void k_attn(
    const float* __restrict__ x, const u16* __restrict__ wbf,
    const int* __restrict__ bidx, const float* __restrict__ seg,
    const int* __restrict__ cnt,
    const float* __restrict__ pal, const float* __restrict__ paa,
    float* __restrict__ out) {
  __shared__ __align__(16) char smem[32768];
  const int tid = threadIdx.x;
  const int wave = tid >> 6, lane = tid & 63;
  const int low = lane & 15, quad = lane >> 4;
  const int node0 = blockIdx.x << 6;
  const float al = pal[0], aa = paa[0];
  const u16* w1l = wbf + 2 * 16384;
  const u16* w2l = wbf + 3 * 16384;
  const u16* w1a = wbf + 4 * 16384;
  const u16* w2a = wbf + 5 * 16384;

  // early: per-node graph id + count (consumed in gather, far later)
  int bb[4];
#pragma unroll
  for (int nt = 0; nt < 4; nt++) bb[nt] = bidx[node0 + nt * 16 + low];
  int cc[4];
#pragma unroll
  for (int nt = 0; nt < 4; nt++) cc[nt] = cnt[bb[nt]];

  // ---- stage x -> swizzled bf16 [64][256] ----
  const float* xsrc = x + (size_t)node0 * CC;
#pragma unroll
  for (int k = 0; k < 16; k++) {
    int f = k * 1024 + tid * 4;
    f32x4 v = *(const f32x4*)(xsrc + f);
    int node = f >> 8;
    u32x2 p;
    p[0] = cvt_pk_bf16(v[0], v[1]);
    p[1] = cvt_pk_bf16(v[2], v[3]);
    *(u32x2*)(smem + SWZ(node * 512 + (f & 255) * 2, node)) = p;
  }
  __syncthreads();

  // ---- local layer1 ----
  f32x4 z[4] = {};
  const u16* w1p = w1l + (wave * 16 + low) * CC;
#pragma unroll
  for (int ks = 0; ks < 8; ks++) {
    short8 wa = *(const short8*)(w1p + ks * 32 + quad * 8);
#pragma unroll
    for (int nt = 0; nt < 4; nt++) {
      int node = nt * 16 + low;
      short8 xf = *(const short8*)(smem + SWZ(node * 512 + ks * 64 + quad * 16, node));
      z[nt] = MFMA16(wa, xf, z[nt]);
    }
  }
  __syncthreads();   // x reads done; z overlay may overwrite
#pragma unroll
  for (int nt = 0; nt < 4; nt++) {
    float v0 = z[nt][0], v1 = z[nt][1], v2 = z[nt][2], v3 = z[nt][3];
    v0 = v0 >= 0.f ? v0 : al * v0;
    v1 = v1 >= 0.f ? v1 : al * v1;
    v2 = v2 >= 0.f ? v2 : al * v2;
    v3 = v3 >= 0.f ? v3 : al * v3;
    int node = nt * 16 + low;
    u32x2 p;
    p[0] = cvt_pk_bf16(v0, v1);
    p[1] = cvt_pk_bf16(v2, v3);
    *(u32x2*)(smem + SWZ(node * 128 + wave * 32 + quad * 8, node)) = p;
  }
  __syncthreads();   // z visible

  // ---- local layer2 -> loc[nt][mt] ----
  f32x4 loc[4][4] = {};
#pragma unroll
  for (int ks2 = 0; ks2 < 2; ks2++) {
    short8 zf[4];
#pragma unroll
    for (int nt = 0; nt < 4; nt++) {
      int node = nt * 16 + low;
      zf[nt] = *(const short8*)(smem + SWZ(node * 128 + ks2 * 64 + quad * 16, node));
    }
#pragma unroll
    for (int mt = 0; mt < 4; mt++) {
      short8 wa = *(const short8*)(w2l + (wave * 64 + mt * 16 + low) * RR + ks2 * 32 + quad * 8);
#pragma unroll
      for (int nt = 0; nt < 4; nt++)
        loc[nt][mt] = MFMA16(wa, zf[nt], loc[nt][mt]);
    }
  }
  __syncthreads();   // z reads done; h overlay may overwrite full 32 KB

  // ---- h = loc + seg_sum[bidx]*(1/cnt) -> swizzled bf16 [64][256] ----
#pragma unroll
  for (int nt = 0; nt < 4; nt++) {
    const float* srow = seg + (size_t)bb[nt] * CC + wave * 64;
    float inv = (cc[nt] > 0) ? __builtin_amdgcn_rcpf((float)cc[nt]) : 0.0f;
    int node = nt * 16 + low;
#pragma unroll
    for (int mt = 0; mt < 4; mt++) {
      f32x4 sv = *(const f32x4*)(srow + mt * 16 + quad * 4);
      u32x2 p;
      p[0] = cvt_pk_bf16(fmaf(sv[0], inv, loc[nt][mt][0]),
                         fmaf(sv[1], inv, loc[nt][mt][1]));
      p[1] = cvt_pk_bf16(fmaf(sv[2], inv, loc[nt][mt][2]),
                         fmaf(sv[3], inv, loc[nt][mt][3]));
      *(u32x2*)(smem + SWZ(node * 512 + wave * 128 + mt * 32 + quad * 8, node)) = p;
    }
  }
  __syncthreads();   // h visible

  // ---- attn layer1 (B-frags from h) ----
  f32x4 z2[4] = {};
  const u16* w1pa = w1a + (wave * 16 + low) * CC;
#pragma unroll
  for (int ks = 0; ks < 8; ks++) {
    short8 wa = *(const short8*)(w1pa + ks * 32 + quad * 8);
#pragma unroll
    for (int nt = 0; nt < 4; nt++) {
      int node = nt * 16 + low;
      short8 hf = *(const short8*)(smem + SWZ(node * 512 + ks * 64 + quad * 16, node));
      z2[nt] = MFMA16(wa, hf, z2[nt]);
    }
  }
  __syncthreads();   // h reads done; z2 overlay may overwrite
#pragma unroll
  for (int nt = 0; nt < 4; nt++) {
    float v0 = z2[nt][0], v1 = z2[nt][1], v2 = z2[nt][2], v3 = z2[nt][3];
    v0 = v0 >= 0.f ? v0 : aa * v0;
    v1 = v1 >= 0.f ? v1 : aa * v1;
    v2 = v2 >= 0.f ? v2 : aa * v2;
    v3 = v3 >= 0.f ? v3 : aa * v3;
    int node = nt * 16 + low;
    u32x2 p;
    p[0] = cvt_pk_bf16(v0, v1);
    p[1] = cvt_pk_bf16(v2, v3);
    *(u32x2*)(smem + SWZ(node * 128 + wave * 32 + quad * 8, node)) = p;
  }
  __syncthreads();   // z2 visible

  // ---- attn layer2 -> o[nt][mt] ----
  f32x4 o[4][4] = {};
#pragma unroll
  for (int ks2 = 0; ks2 < 2; ks2++) {
    short8 zf[4];
#pragma unroll
    for (int nt = 0; nt < 4; nt++) {
      int node = nt * 16 + low;
      zf[nt] = *(const short8*)(smem + SWZ(node * 128 + ks2 * 64 + quad * 16, node));
    }
#pragma unroll
    for (int mt = 0; mt < 4; mt++) {
      short8 wa = *(const short8*)(w2a + (wave * 64 + mt * 16 + low) * RR + ks2 * 32 + quad * 8);
#pragma unroll
      for (int nt = 0; nt < 4; nt++)
        o[nt][mt] = MFMA16(wa, zf[nt], o[nt][mt]);
    }
  }
  // sigmoid (v_exp + v_rcp)
#pragma unroll
  for (int nt = 0; nt < 4; nt++)
#pragma unroll
    for (int mt = 0; mt < 4; mt++)
#pragma unroll
      for (int i = 0; i < 4; i++)
        o[nt][mt][i] = __builtin_amdgcn_rcpf(1.0f + __expf(-o[nt][mt][i]));
  __syncthreads();   // z2 reads done; slab overlay may overwrite

  // ---- coalesced store via per-wave [16][68] f32 slabs ----
  float* slab = (float*)(smem + wave * 4352);
#pragma unroll
  for (int nt = 0; nt < 4; nt++) {
#pragma unroll
    for (int mt = 0; mt < 4; mt++)
      *(f32x4*)(slab + low * 68 + mt * 16 + quad * 4) = o[nt][mt];
    lgkm0();
#pragma unroll
    for (int n = 0; n < 16; n++)
      out[(size_t)(node0 + nt * 16 + n) * CC + wave * 64 + lane] = slab[n * 68 + lane];
    lgkm0();
  }
}

extern "C" void kernel_launch(void* const* d_in, const int* in_sizes, int n_in,
                              void* d_out, int out_size, void* d_ws, size_t ws_size,
                              hipStream_t stream) {
  (void)in_sizes; (void)n_in; (void)out_size; (void)ws_size;
  const float* x   = (const float*)d_in[0];
  const float* w1g = (const float*)d_in[1];
  const float* ag  = (const float*)d_in[2];
  const float* w2g = (const float*)d_in[3];
  const float* w1l = (const float*)d_in[4];
  const float* al  = (const float*)d_in[5];
  const float* w2l = (const float*)d_in[6];
  const float* w1a = (const float*)d_in[7];
  const float* aa  = (const float*)d_in[8];
  const float* w2a = (const float*)d_in[9];
  const int* bidx  = (const int*)d_in[10];
  float* out = (float*)d_out;

  u16* wbf   = (u16*)d_ws;
  float* seg = (float*)((char*)d_ws + 196608);
  int* cnt   = (int*)((char*)d_ws + 196608 + 1048576);

  hipMemsetAsync(seg, 0, 1048576 + 4096, stream);
  k_cvt<<<96, 256, 0, stream>>>(w1g, w2g, w1l, w2l, w1a, w2a, wbf);
  k_glb<<<NN / 64, 256, 0, stream>>>(x, wbf, bidx, ag, seg, cnt);
  k_attn<<<NN / 64, 256, 0, stream>>>(x, wbf, bidx, seg, cnt, al, aa, out);
}

// Round 4
// 666.151 us; speedup vs baseline: 1.0992x; 1.0992x over previous
//
#include <hip/hip_runtime.h>

typedef unsigned short u16;
typedef __attribute__((ext_vector_type(8))) short short8;
typedef __attribute__((ext_vector_type(4))) float f32x4;
typedef __attribute__((ext_vector_type(4))) unsigned short u16x4;
typedef __attribute__((ext_vector_type(2))) unsigned u32x2;

#define NN 262144
#define CC 256
#define RR 64
#define GG 1024

// LDS byte-offset swizzle for row-major [node][feat] bf16 tiles: XOR node low
// bits into the 16B-slot bits -> 2-way max bank aliasing on ds_read_b128 (free).
#define SWZ(b, n) ((b) ^ (((n) & 7) << 4))

// ws layout (bytes):
//   0        : 6 bf16 weight matrices, 16384 elems each (w1g,w2g,w1l,w2l,w1a,w2a)
//   196608   : seg float [1024][256]  (raw sums; k_attn scales by 1/cnt)
//   1245184  : cnt int [1024]

static __device__ __forceinline__ u16 f2bf(float f) {
  unsigned u = __builtin_bit_cast(unsigned, f);
  u += 0x7fffu + ((u >> 16) & 1u);   // RNE to bf16
  return (u16)(u >> 16);
}

static __device__ __forceinline__ unsigned cvt_pk_bf16(float lo, float hi) {
  unsigned r;
  asm("v_cvt_pk_bf16_f32 %0, %1, %2" : "=v"(r) : "v"(lo), "v"(hi));
  return r;
}

static __device__ __forceinline__ void lgkm0() {
  __asm__ volatile("s_waitcnt lgkmcnt(0)" ::: "memory");
}

#define MFMA16(a, b, c) __builtin_amdgcn_mfma_f32_16x16x32_bf16((a), (b), (c), 0, 0, 0)

// ---- weight fp32 -> bf16 conversion ----
__global__ void k_cvt(const float* __restrict__ a0, const float* __restrict__ a1,
                      const float* __restrict__ a2, const float* __restrict__ a3,
                      const float* __restrict__ a4, const float* __restrict__ a5,
                      u16* __restrict__ dst) {
  int m = blockIdx.x >> 4;
  const float* s = (m == 0) ? a0 : (m == 1) ? a1 : (m == 2) ? a2
                 : (m == 3) ? a3 : (m == 4) ? a4 : a5;
  int off = (((blockIdx.x & 15) << 8) | threadIdx.x) << 2;
  f32x4 v = *(const f32x4*)(s + off);
  u16x4 p;
  p[0] = f2bf(v[0]); p[1] = f2bf(v[1]); p[2] = f2bf(v[2]); p[3] = f2bf(v[3]);
  *(u16x4*)(dst + m * 16384 + off) = p;
}

// ============================================================================
// Block = 64 nodes, 4 waves, feature-split. Per-nt layer2 processing keeps
// peak live regs ~50 (no acc[4][4] arrays). amdgpu_waves_per_eu pins the
// regalloc occupancy target so it allocates VGPRs instead of spilling
// (R3 lesson: default regalloc chases 10 waves/EU and spills ~400 MB).
// ============================================================================

// ---- K1: glb MLP + segment sums/counts ----
// LDS 32768 (5 blocks/CU = 160 KB): x 0..32768 (node*512 swz, dead after L1);
// z overlay 0..8192 (node*128 swz); slabs 8192+wave*4352 (..25600, disjoint
// from z -> per-nt reduce needs no barrier); lb 25600..25856.
__global__ __launch_bounds__(256)
__attribute__((amdgpu_waves_per_eu(5, 5))) void k_glb(
    const float* __restrict__ x, const u16* __restrict__ wbf,
    const int* __restrict__ bidx, const float* __restrict__ pa,
    float* __restrict__ seg, int* __restrict__ cnt) {
  __shared__ __align__(16) char smem[32768];
  const int tid = threadIdx.x;
  const int wave = tid >> 6, lane = tid & 63;
  const int low = lane & 15, quad = lane >> 4;
  const int node0 = blockIdx.x << 6;
  const float alpha = pa[0];
  const u16* w1 = wbf;              // glb_w1 [64][256]
  const u16* w2 = wbf + 16384;      // glb_w2 [256][64]

  // early: bidx into register (stored to LDS after x is dead)
  int myb_lb = (tid < 64) ? bidx[node0 + tid] : 0;

  // ---- stage x -> swizzled bf16 [64][256] ----
  const float* xsrc = x + (size_t)node0 * CC;
#pragma unroll
  for (int k = 0; k < 16; k++) {
    int f = k * 1024 + tid * 4;
    f32x4 v = *(const f32x4*)(xsrc + f);
    int node = f >> 8;
    u32x2 p;
    p[0] = cvt_pk_bf16(v[0], v[1]);
    p[1] = cvt_pk_bf16(v[2], v[3]);
    *(u32x2*)(smem + SWZ(node * 512 + (f & 255) * 2, node)) = p;
  }
  __syncthreads();   // B1: x visible

  // ---- layer1: wave's 16 feats x all 64 nodes ----
  f32x4 z[4] = {};
  const u16* w1p = w1 + (wave * 16 + low) * CC;
#pragma unroll
  for (int ks = 0; ks < 8; ks++) {
    short8 wa = *(const short8*)(w1p + ks * 32 + quad * 8);
#pragma unroll
    for (int nt = 0; nt < 4; nt++) {
      int node = nt * 16 + low;
      short8 xf = *(const short8*)(smem + SWZ(node * 512 + ks * 64 + quad * 16, node));
      z[nt] = MFMA16(wa, xf, z[nt]);
    }
  }
  __syncthreads();   // B2: all x reads drained; z/lb overlay may overwrite

  if (tid < 64) ((int*)(smem + 25600))[tid] = myb_lb;
#pragma unroll
  for (int nt = 0; nt < 4; nt++) {
    float v0 = z[nt][0], v1 = z[nt][1], v2 = z[nt][2], v3 = z[nt][3];
    v0 = v0 >= 0.f ? v0 : alpha * v0;
    v1 = v1 >= 0.f ? v1 : alpha * v1;
    v2 = v2 >= 0.f ? v2 : alpha * v2;
    v3 = v3 >= 0.f ? v3 : alpha * v3;
    int node = nt * 16 + low;
    u32x2 p;
    p[0] = cvt_pk_bf16(v0, v1);
    p[1] = cvt_pk_bf16(v2, v3);
    *(u32x2*)(smem + SWZ(node * 128 + wave * 32 + quad * 8, node)) = p;
  }
  __syncthreads();   // B3: z + lb visible

  const int* lbp = (const int*)(smem + 25600);

  // node counts (per-wave 16-node chunk, run-length on sorted bidx)
  if (lane == 0) {
    int base = wave * 16;
    int cur = lbp[base], rl = 0;
#pragma unroll
    for (int n = 0; n < 16; n++) {
      int b = lbp[base + n];
      if (b != cur) { atomicAdd(cnt + cur, rl); rl = 0; cur = b; }
      rl++;
    }
    atomicAdd(cnt + cur, rl);
  }

  // ---- layer2 + segment reduce, per nt (acc[4] only; slab disjoint from z) ----
  float* slab = (float*)(smem + 8192 + wave * 4352);
#pragma unroll
  for (int nt = 0; nt < 4; nt++) {
    int node = nt * 16 + low;
    f32x4 g[4] = {};
#pragma unroll
    for (int ks2 = 0; ks2 < 2; ks2++) {
      short8 zf = *(const short8*)(smem + SWZ(node * 128 + ks2 * 64 + quad * 16, node));
#pragma unroll
      for (int mt = 0; mt < 4; mt++) {
        short8 wa = *(const short8*)(w2 + (wave * 64 + mt * 16 + low) * RR + ks2 * 32 + quad * 8);
        g[mt] = MFMA16(wa, zf, g[mt]);
      }
    }
#pragma unroll
    for (int mt = 0; mt < 4; mt++)
      *(f32x4*)(slab + low * 68 + mt * 16 + quad * 4) = g[mt];
    lgkm0();
    float acc = 0.f;
    int cur = lbp[nt * 16];
#pragma unroll
    for (int n = 0; n < 16; n++) {
      int b = lbp[nt * 16 + n];
      if (b != cur) {
        atomicAdd(seg + (size_t)cur * CC + wave * 64 + lane, acc);
        acc = 0.f; cur = b;
      }
      acc += slab[n * 68 + lane];
    }
    atomicAdd(seg + (size_t)cur * CC + wave * 64 + lane, acc);
    lgkm0();   // slab reads drained before next nt overwrites
  }
}

// ---- K3: local MLP + gather(1/cnt fused) + attn MLP + sigmoid ----
// LDS 40960 (4 blocks/CU = 160 KB): x/h 0..32768 (node*512 swz);
// z/z2 32768..40960 (node*128 swz) DISJOINT -> per-nt h-stage needs no
// barrier; out slabs wave*4352 overlay x/h region after B4.
#define ZBOFF 32768
__global__ __launch_bounds__(256)
__attribute__((amdgpu_waves_per_eu(4, 4))) void k_attn(
    const float* __restrict__ x, const u16* __restrict__ wbf,
    const int* __restrict__ bidx, const float* __restrict__ seg,
    const int* __restrict__ cnt,
    const float* __restrict__ pal, const float* __restrict__ paa,
    float* __restrict__ out) {
  __shared__ __align__(16) char smem[40960];
  const int tid = threadIdx.x;
  const int wave = tid >> 6, lane = tid & 63;
  const int low = lane & 15, quad = lane >> 4;
  const int node0 = blockIdx.x << 6;
  const float al = pal[0], aa = paa[0];
  const u16* w1l = wbf + 2 * 16384;
  const u16* w2l = wbf + 3 * 16384;
  const u16* w1a = wbf + 4 * 16384;
  const u16* w2a = wbf + 5 * 16384;

  // early: per-node graph id + count (consumed in gather, far later)
  int bb[4];
#pragma unroll
  for (int nt = 0; nt < 4; nt++) bb[nt] = bidx[node0 + nt * 16 + low];
  int cc[4];
#pragma unroll
  for (int nt = 0; nt < 4; nt++) cc[nt] = cnt[bb[nt]];

  // ---- stage x -> swizzled bf16 [64][256] ----
  const float* xsrc = x + (size_t)node0 * CC;
#pragma unroll
  for (int k = 0; k < 16; k++) {
    int f = k * 1024 + tid * 4;
    f32x4 v = *(const f32x4*)(xsrc + f);
    int node = f >> 8;
    u32x2 p;
    p[0] = cvt_pk_bf16(v[0], v[1]);
    p[1] = cvt_pk_bf16(v[2], v[3]);
    *(u32x2*)(smem + SWZ(node * 512 + (f & 255) * 2, node)) = p;
  }
  __syncthreads();   // B1: x visible

  // ---- local layer1 ----
  f32x4 z[4] = {};
  const u16* w1p = w1l + (wave * 16 + low) * CC;
#pragma unroll
  for (int ks = 0; ks < 8; ks++) {
    short8 wa = *(const short8*)(w1p + ks * 32 + quad * 8);
#pragma unroll
    for (int nt = 0; nt < 4; nt++) {
      int node = nt * 16 + low;
      short8 xf = *(const short8*)(smem + SWZ(node * 512 + ks * 64 + quad * 16, node));
      z[nt] = MFMA16(wa, xf, z[nt]);
    }
  }
  // z overlay lives at ZBOFF (disjoint from x) -> write without extra barrier
#pragma unroll
  for (int nt = 0; nt < 4; nt++) {
    float v0 = z[nt][0], v1 = z[nt][1], v2 = z[nt][2], v3 = z[nt][3];
    v0 = v0 >= 0.f ? v0 : al * v0;
    v1 = v1 >= 0.f ? v1 : al * v1;
    v2 = v2 >= 0.f ? v2 : al * v2;
    v3 = v3 >= 0.f ? v3 : al * v3;
    int node = nt * 16 + low;
    u32x2 p;
    p[0] = cvt_pk_bf16(v0, v1);
    p[1] = cvt_pk_bf16(v2, v3);
    *(u32x2*)(smem + ZBOFF + SWZ(node * 128 + wave * 32 + quad * 8, node)) = p;
  }
  __syncthreads();   // B2: z visible + x reads drained (h may overwrite x)

  // ---- layer2 + gather + h-stage, per nt (loc[4] only; h disjoint from z) ----
#pragma unroll
  for (int nt = 0; nt < 4; nt++) {
    int node = nt * 16 + low;
    f32x4 loc[4] = {};
#pragma unroll
    for (int ks2 = 0; ks2 < 2; ks2++) {
      short8 zf = *(const short8*)(smem + ZBOFF + SWZ(node * 128 + ks2 * 64 + quad * 16, node));
#pragma unroll
      for (int mt = 0; mt < 4; mt++) {
        short8 wa = *(const short8*)(w2l + (wave * 64 + mt * 16 + low) * RR + ks2 * 32 + quad * 8);
        loc[mt] = MFMA16(wa, zf, loc[mt]);
      }
    }
    const float* srow = seg + (size_t)bb[nt] * CC + wave * 64;
    float inv = (cc[nt] > 0) ? __builtin_amdgcn_rcpf((float)cc[nt]) : 0.0f;
#pragma unroll
    for (int mt = 0; mt < 4; mt++) {
      f32x4 sv = *(const f32x4*)(srow + mt * 16 + quad * 4);
      u32x2 p;
      p[0] = cvt_pk_bf16(fmaf(sv[0], inv, loc[mt][0]),
                         fmaf(sv[1], inv, loc[mt][1]));
      p[1] = cvt_pk_bf16(fmaf(sv[2], inv, loc[mt][2]),
                         fmaf(sv[3], inv, loc[mt][3]));
      *(u32x2*)(smem + SWZ(node * 512 + wave * 128 + mt * 32 + quad * 8, node)) = p;
    }
  }
  __syncthreads();   // B3: h visible + z reads drained

  // ---- attn layer1 (B-frags from h); z2 -> ZBOFF (disjoint from h) ----
  f32x4 z2[4] = {};
  const u16* w1pa = w1a + (wave * 16 + low) * CC;
#pragma unroll
  for (int ks = 0; ks < 8; ks++) {
    short8 wa = *(const short8*)(w1pa + ks * 32 + quad * 8);
#pragma unroll
    for (int nt = 0; nt < 4; nt++) {
      int node = nt * 16 + low;
      short8 hf = *(const short8*)(smem + SWZ(node * 512 + ks * 64 + quad * 16, node));
      z2[nt] = MFMA16(wa, hf, z2[nt]);
    }
  }
#pragma unroll
  for (int nt = 0; nt < 4; nt++) {
    float v0 = z2[nt][0], v1 = z2[nt][1], v2 = z2[nt][2], v3 = z2[nt][3];
    v0 = v0 >= 0.f ? v0 : aa * v0;
    v1 = v1 >= 0.f ? v1 : aa * v1;
    v2 = v2 >= 0.f ? v2 : aa * v2;
    v3 = v3 >= 0.f ? v3 : aa * v3;
    int node = nt * 16 + low;
    u32x2 p;
    p[0] = cvt_pk_bf16(v0, v1);
    p[1] = cvt_pk_bf16(v2, v3);
    *(u32x2*)(smem + ZBOFF + SWZ(node * 128 + wave * 32 + quad * 8, node)) = p;
  }
  __syncthreads();   // B4: z2 visible + h reads drained (slab may overwrite)

  // ---- attn layer2 + sigmoid + store, per nt (o[4] only) ----
  float* slab = (float*)(smem + wave * 4352);
#pragma unroll
  for (int nt = 0; nt < 4; nt++) {
    int node = nt * 16 + low;
    f32x4 o[4] = {};
#pragma unroll
    for (int ks2 = 0; ks2 < 2; ks2++) {
      short8 zf = *(const short8*)(smem + ZBOFF + SWZ(node * 128 + ks2 * 64 + quad * 16, node));
#pragma unroll
      for (int mt = 0; mt < 4; mt++) {
        short8 wa = *(const short8*)(w2a + (wave * 64 + mt * 16 + low) * RR + ks2 * 32 + quad * 8);
        o[mt] = MFMA16(wa, zf, o[mt]);
      }
    }
#pragma unroll
    for (int mt = 0; mt < 4; mt++) {
#pragma unroll
      for (int i = 0; i < 4; i++)
        o[mt][i] = __builtin_amdgcn_rcpf(1.0f + __expf(-o[mt][i]));
      *(f32x4*)(slab + low * 68 + mt * 16 + quad * 4) = o[mt];
    }
    lgkm0();
#pragma unroll
    for (int n = 0; n < 16; n++)
      out[(size_t)(node0 + nt * 16 + n) * CC + wave * 64 + lane] = slab[n * 68 + lane];
    lgkm0();   // slab reads drained before next nt overwrites
  }
}

extern "C" void kernel_launch(void* const* d_in, const int* in_sizes, int n_in,
                              void* d_out, int out_size, void* d_ws, size_t ws_size,
                              hipStream_t stream) {
  (void)in_sizes; (void)n_in; (void)out_size; (void)ws_size;
  const float* x   = (const float*)d_in[0];
  const float* w1g = (const float*)d_in[1];
  const float* ag  = (const float*)d_in[2];
  const float* w2g = (const float*)d_in[3];
  const float* w1l = (const float*)d_in[4];
  const float* al  = (const float*)d_in[5];
  const float* w2l = (const float*)d_in[6];
  const float* w1a = (const float*)d_in[7];
  const float* aa  = (const float*)d_in[8];
  const float* w2a = (const float*)d_in[9];
  const int* bidx  = (const int*)d_in[10];
  float* out = (float*)d_out;

  u16* wbf   = (u16*)d_ws;
  float* seg = (float*)((char*)d_ws + 196608);
  int* cnt   = (int*)((char*)d_ws + 196608 + 1048576);

  hipMemsetAsync(seg, 0, 1048576 + 4096, stream);
  k_cvt<<<96, 256, 0, stream>>>(w1g, w2g, w1l, w2l, w1a, w2a, wbf);
  k_glb<<<NN / 64, 256, 0, stream>>>(x, wbf, bidx, ag, seg, cnt);
  k_attn<<<NN / 64, 256, 0, stream>>>(x, wbf, bidx, seg, cnt, al, aa, out);
}